// Round 1
// 411.456 us; speedup vs baseline: 1.0030x; 1.0030x over previous
//
#include <hip/hip_runtime.h>

// Cost volume: out[n,c,d,h,w] = left[n,c,h,w] * right[n,c,h,w-d] (w>=d else 0)
// N=2 C=32 H=136 W=240 D=48. Output 401 MB fp32 -> write-BW bound.
// Round-3 rewrite: the old loop did 4x bank-conflicted ds_read_b32 (lane stride
// 4 floats -> 8-way conflict) + a magic-div per float4. Now we stage FOUR
// shifted copies of the padded right row so that for d = 4q+j the read is an
// aligned conflict-free ds_read_b128 from copy j at float4 index (12+lane-q).
// Each wave owns 12 consecutive d-planes, each lane owns one w4; left is a
// single register float4 per lane; d-loop fully unrolled (no div, no per-iter
// 64-bit mul). Stores stay 960B-contiguous nontemporal dwordx4.

constexpr int W    = 240;
constexpr int H    = 136;
constexpr int D    = 48;
constexpr int W4   = W / 4;          // 60 float4 per row
constexpr int PAD  = D;              // 48 zero floats of left padding
constexpr int PAD4 = PAD / 4;        // 12
constexpr int CLEN = PAD + W;        // 288 floats per shifted copy (1152 B, 16B-mult)

typedef float v4f __attribute__((ext_vector_type(4)));

__global__ __launch_bounds__(256) void cost_volume_kernel(
    const float* __restrict__ left,
    const float* __restrict__ right,
    float* __restrict__ out)
{
    __shared__ __align__(16) float sC[4][CLEN];   // sC[j][x] = R[x-48-j], 0 if OOB

    const int h    = blockIdx.x;     // 0..H-1
    const int nc   = blockIdx.y;     // 0..N*C-1
    const int tid  = threadIdx.x;
    const int wave = tid >> 6;       // 0..3
    const int lane = tid & 63;
    const size_t row = (size_t)(nc * H + h) * W;

    // Issue the left load early so its cold-HBM latency overlaps staging.
    v4f l4 = (v4f){0.f, 0.f, 0.f, 0.f};
    if (lane < W4) l4 = reinterpret_cast<const v4f*>(left + row)[lane];

    // Stage 4 shifted copies of the right row: 4*288 = 1152 scalar writes.
    // Consecutive tid -> consecutive addresses (coalesced reads, no LDS
    // write conflicts). Runs only ~5 iterations; the magic-div is fine here.
    for (int y = tid; y < 4 * CLEN; y += 256) {
        const int j = y / CLEN;
        const int x = y - j * CLEN;
        const int r = x - PAD - j;
        sC[j][x] = (r >= 0) ? right[row + r] : 0.0f;
    }
    __syncthreads();

    if (lane >= W4) return;          // 60 active lanes/wave; after the barrier

    const v4f* C0 = reinterpret_cast<const v4f*>(sC[0]);
    const v4f* C1 = reinterpret_cast<const v4f*>(sC[1]);
    const v4f* C2 = reinterpret_cast<const v4f*>(sC[2]);
    const v4f* C3 = reinterpret_cast<const v4f*>(sC[3]);

    const int d0 = wave * (D / 4);   // 12 d-planes per wave: d in [d0, d0+12)
    // out base for (nc, d0, h), this lane's float4 slot
    v4f* out4 = reinterpret_cast<v4f*>(out)
              + (((size_t)nc * D + d0) * H + h) * (size_t)W4 + lane;
    const size_t ds4 = (size_t)H * W4;   // float4 stride between d-planes

    #pragma unroll
    for (int tt = 0; tt < 3; ++tt) {
        // d = d0 + 4*tt + j ; q = d/4 = 3*wave + tt (d0 % 4 == 0)
        const int q    = 3 * wave + tt;
        const int base = PAD4 + lane - q;     // >= 1 always
        // element k of Cj[base] = R[4*lane + k - (4q+j)] = R[w + k - d]
        const v4f r0 = C0[base];
        const v4f r1 = C1[base];
        const v4f r2 = C2[base];
        const v4f r3 = C3[base];
        v4f* o = out4 + (size_t)(4 * tt) * ds4;
        __builtin_nontemporal_store(l4 * r0, o);
        __builtin_nontemporal_store(l4 * r1, o + ds4);
        __builtin_nontemporal_store(l4 * r2, o + 2 * ds4);
        __builtin_nontemporal_store(l4 * r3, o + 3 * ds4);
    }
}

extern "C" void kernel_launch(void* const* d_in, const int* in_sizes, int n_in,
                              void* d_out, int out_size, void* d_ws, size_t ws_size,
                              hipStream_t stream) {
    const float* left  = (const float*)d_in[0];
    const float* right = (const float*)d_in[1];
    float* out = (float*)d_out;
    const int rows = in_sizes[0] / W;   // N*C*H = 8704
    const int nc   = rows / H;          // N*C = 64
    dim3 grid(H, nc);
    cost_volume_kernel<<<grid, 256, 0, stream>>>(left, right, out);
}